// Round 6
// baseline (407.856 us; speedup 1.0000x reference)
//
#include <hip/hip_runtime.h>
#include <hip/hip_bf16.h>

typedef short  short8  __attribute__((ext_vector_type(8)));
typedef float  float4v __attribute__((ext_vector_type(4)));

#define SEQ    4096
#define DHEAD  64
#define NBLK   64
#define LSTR   72        // LDS row stride in bf16 elems for P buffer
#define NCHUNK 8         // split factor for full rows (qb 0, 63)
#define CHK    8         // key blocks per split chunk
#define WGPB   78        // units per (b,h): 62 regular + 2*8 split
#define ENTRY_FLOATS 4160   // per split-partial: 64 l + 64*64 o
#define KS_ELEMS (2L * 16 * 4096 * 64)   // bf16 K copy elems (= 16 MB)
// ws layout: [0,16MB) Ks bf16 | [16MB,32MB) VT bf16 | [32MB, ...) partials fp32

__device__ __forceinline__ short f2bf(float f) {
    unsigned u = __float_as_uint(f);
    u += 0x7fffu + ((u >> 16) & 1u);   // RNE to bf16
    return (short)(u >> 16);
}

// ---------------- prep: fp32 -> bf16, V transposed per 64x64 block ----------------
__global__ __launch_bounds__(256)
void bigbird_prep(const float* __restrict__ K,
                  const float* __restrict__ V,
                  short* __restrict__ wsS) {
    __shared__ float tile[64 * 65];
    const int bh = blockIdx.x >> 6;
    const int kb = blockIdx.x & 63;
    const int t  = threadIdx.x;
    short* Ks = wsS;
    short* VT = wsS + KS_ELEMS;

    const int row = t >> 2, seg = t & 3;
    const long gsrc = ((long)bh * SEQ + kb * 64 + row) * DHEAD + seg * 16;
    const long blk  = ((long)(bh * 64 + kb) * 64);

    // K: straight convert, coalesced
    {
        const float* kp = K + gsrc;
        short8 s0, s1;
#pragma unroll
        for (int i = 0; i < 4; ++i) {
            float4v x = ((const float4v*)kp)[i];
#pragma unroll
            for (int jj = 0; jj < 4; ++jj) {
                short v = f2bf(x[jj]);
                if (i < 2) s0[i * 4 + jj] = v; else s1[(i - 2) * 4 + jj] = v;
            }
        }
        *(short8*)(Ks + (blk + row) * 64 + seg * 16)     = s0;
        *(short8*)(Ks + (blk + row) * 64 + seg * 16 + 8) = s1;
    }
    // V: through LDS transpose
    {
        const float* vp = V + gsrc;
#pragma unroll
        for (int i = 0; i < 4; ++i) {
            float4v x = ((const float4v*)vp)[i];
#pragma unroll
            for (int jj = 0; jj < 4; ++jj)
                tile[row * 65 + seg * 16 + i * 4 + jj] = x[jj];
        }
    }
    __syncthreads();
    {
        const int d = t >> 2, kk = t & 3;
        short8 s0, s1;
#pragma unroll
        for (int i = 0; i < 8; ++i) {
            s0[i] = f2bf(tile[(kk * 16 + i) * 65 + d]);
            s1[i] = f2bf(tile[(kk * 16 + 8 + i) * 65 + d]);
        }
        *(short8*)(VT + (blk + d) * 64 + kk * 16)     = s0;
        *(short8*)(VT + (blk + d) * 64 + kk * 16 + 8) = s1;
    }
}

// ---------------- main: one unit per WG, 4 independent waves (rows w*16..+15),
// ---------------- zero barriers, K/V B-frags straight from bf16 ws ----------------
__global__ __launch_bounds__(256, 6)
void bigbird_main(const float* __restrict__ Q,
                  const int* __restrict__ rand_attn,
                  float* __restrict__ out,
                  const short* __restrict__ wsS,
                  float* __restrict__ part) {
    __shared__ short pb_s[4 * 16 * LSTR];   // per-wave P (wave-private slice)
    __shared__ int   kl_s[4][8];            // per-wave key-block list copy

    const int tid  = threadIdx.x;
    const int wave = tid >> 6;
    const int lane = tid & 63;
    const int l15  = lane & 15;
    const int quad = lane >> 4;

    const int unit = blockIdx.x;                // 2496 units, one per WG
    const int bh   = unit / WGPB;
    const int j    = unit - bh * WGPB;
    const bool split = (j >= 62);
    int qb, chunk = 0, nk;
    if (!split) { qb = j + 1; nk = (qb == 1 || qb == 62) ? 7 : 8; }
    else        { int s2 = j - 62; qb = (s2 >> 3) ? 63 : 0; chunk = s2 & 7; nk = CHK; }

    const long base = (long)bh * SEQ * DHEAD;
    const short* Ks = wsS + (long)bh * (NBLK * 64 * 64);
    const short* VT = wsS + KS_ELEMS + (long)bh * (NBLK * 64 * 64);

    // per-wave key-block list (each wave writes & reads its own copy: no barrier)
    if (!split && lane < 8) {
        const int rbase = (bh * 62 + (qb - 1)) * 3;
        int v = 0;
        if (qb == 1) {
            v = (lane == 0) ? 0 : (lane == 1) ? 1 : (lane == 2) ? 2 : (lane == 3) ? 63
                : (lane < 7 ? rand_attn[rbase + lane - 4] : 0);
        } else if (qb == 62) {
            v = (lane == 0) ? 0 : (lane == 1) ? 61 : (lane == 2) ? 62 : (lane == 3) ? 63
                : (lane < 7 ? rand_attn[rbase + lane - 4] : 0);
        } else {
            v = (lane == 0) ? 0 : (lane == 1) ? (qb - 1) : (lane == 2) ? qb
                : (lane == 3) ? (qb + 1) : (lane == 4) ? 63
                : rand_attn[rbase + lane - 5];
        }
        kl_s[wave][lane] = v;
    }

    // Q fragments from fp32, pre-scaled by 1/8 (exact); wave covers rows wave*16..+15
    short8 aq0, aq1;
    {
        const float* qp = Q + base + (long)(qb * 64 + wave * 16 + l15) * DHEAD + quad * 8;
        float4v x0 = *(const float4v*)(qp);
        float4v x1 = *(const float4v*)(qp + 4);
        float4v x2 = *(const float4v*)(qp + 32);
        float4v x3 = *(const float4v*)(qp + 36);
#pragma unroll
        for (int i = 0; i < 4; ++i) {
            aq0[i]     = f2bf(0.125f * x0[i]);
            aq0[4 + i] = f2bf(0.125f * x1[i]);
            aq1[i]     = f2bf(0.125f * x2[i]);
            aq1[4 + i] = f2bf(0.125f * x3[i]);
        }
    }

    float4v o[4];
    float l_r[4];
#pragma unroll
    for (int nt = 0; nt < 4; ++nt) o[nt] = (float4v)0.0f;
#pragma unroll
    for (int r = 0; r < 4; ++r) l_r[r] = 0.0f;

    short* pw = pb_s + wave * (16 * LSTR);

    for (int it = 0; it < nk; ++it) {
        const int kb = split ? (chunk * CHK + it) : kl_s[wave][it];
        const long blk = (long)kb * (64 * 64);

        // ---- S = Q*K^T ; K B-frags straight from global bf16 (L1/L2-resident) ----
        float4v s[4];
#pragma unroll
        for (int nt = 0; nt < 4; ++nt) {
            const short* kg = Ks + blk + (long)(nt * 16 + l15) * 64 + quad * 8;
            short8 b0 = *(const short8*)(kg);
            short8 b1 = *(const short8*)(kg + 32);
            float4v acc = (float4v)0.0f;
            acc = __builtin_amdgcn_mfma_f32_16x16x32_bf16(aq0, b0, acc, 0, 0, 0);
            acc = __builtin_amdgcn_mfma_f32_16x16x32_bf16(aq1, b1, acc, 0, 0, 0);
            s[nt] = acc;
        }

        // ---- fixed-max softmax: P = exp(S); per-lane partial l ----
#pragma unroll
        for (int r = 0; r < 4; ++r) {
            float rs = 0.0f;
#pragma unroll
            for (int nt = 0; nt < 4; ++nt) {
                const float e = __expf(s[nt][r]);
                s[nt][r] = e;
                rs += e;
            }
            l_r[r] += rs;
#pragma unroll
            for (int nt = 0; nt < 4; ++nt)
                pw[(quad * 4 + r) * LSTR + nt * 16 + l15] = f2bf(s[nt][r]);
        }

        // ---- O += P*V ; V^T B-frags straight from global bf16 ----
#pragma unroll
        for (int f = 0; f < 2; ++f) {
            short8 ap = *(const short8*)(pw + l15 * LSTR + f * 32 + quad * 8);
#pragma unroll
            for (int nt = 0; nt < 4; ++nt) {
                const short* vg = VT + blk + (long)(nt * 16 + l15) * 64 + f * 32 + quad * 8;
                short8 bv = *(const short8*)(vg);
                o[nt] = __builtin_amdgcn_mfma_f32_16x16x32_bf16(ap, bv, o[nt], 0, 0, 0);
            }
        }
    }

    // reduce l across the quad's 16 lanes (once)
#pragma unroll
    for (int r = 0; r < 4; ++r) {
        float rs = l_r[r];
        rs += __shfl_xor(rs, 1, 64);
        rs += __shfl_xor(rs, 2, 64);
        rs += __shfl_xor(rs, 4, 64);
        rs += __shfl_xor(rs, 8, 64);
        l_r[r] = rs;
    }

    if (!split) {
        float* op = out + base + (long)(qb * 64 + wave * 16) * DHEAD;
#pragma unroll
        for (int r = 0; r < 4; ++r) {
            const float inv = 1.0f / l_r[r];
#pragma unroll
            for (int nt = 0; nt < 4; ++nt)
                op[(long)(quad * 4 + r) * DHEAD + nt * 16 + l15] = o[nt][r] * inv;
        }
    } else {
        float* wsp = part + (long)((bh * 2 + (qb == 63)) * NCHUNK + chunk) * ENTRY_FLOATS;
#pragma unroll
        for (int r = 0; r < 4; ++r) {
            const int row = wave * 16 + quad * 4 + r;
            if (l15 == 0) wsp[row] = l_r[r];
#pragma unroll
            for (int nt = 0; nt < 4; ++nt)
                wsp[64 + row * 64 + nt * 16 + l15] = o[nt][r];
        }
    }
}

// ---------------- combine for split rows (plain sums; fixed-max softmax) ----------------
__global__ __launch_bounds__(256)
void bigbird_combine(const float* __restrict__ part, float* __restrict__ out) {
    const int gid = blockIdx.x * 256 + threadIdx.x;   // 262144 total
    const int dim = gid & 63;
    const int row = (gid >> 6) & 63;
    const int sel = (gid >> 12) & 1;
    const int bh  = gid >> 13;

    float num = 0.0f, den = 0.0f;
#pragma unroll
    for (int c = 0; c < NCHUNK; ++c) {
        const float* e = part + (long)((bh * 2 + sel) * NCHUNK + c) * ENTRY_FLOATS;
        den += e[row];
        num += e[64 + row * 64 + dim];
    }
    const int qb = sel ? 63 : 0;
    out[((long)bh * SEQ + qb * 64 + row) * DHEAD + dim] = num / den;
}

extern "C" void kernel_launch(void* const* d_in, const int* in_sizes, int n_in,
                              void* d_out, int out_size, void* d_ws, size_t ws_size,
                              hipStream_t stream) {
    const float* Q       = (const float*)d_in[0];
    const float* K       = (const float*)d_in[1];
    const float* V       = (const float*)d_in[2];
    const int* rand_attn = (const int*)d_in[3];
    float* out           = (float*)d_out;
    short* wsS           = (short*)d_ws;
    float* part          = (float*)((char*)d_ws + 2L * KS_ELEMS * sizeof(short));

    const int B = 2, H = 16;
    bigbird_prep<<<dim3(B * H * NBLK), dim3(256), 0, stream>>>(K, V, wsS);
    bigbird_main<<<dim3(B * H * WGPB), dim3(256), 0, stream>>>(Q, rand_attn, out, wsS, part);
    bigbird_combine<<<dim3((B * H * 2 * 64 * 64) / 256), dim3(256), 0, stream>>>(part, out);
}

// Round 7
// 354.645 us; speedup vs baseline: 1.1500x; 1.1500x over previous
//
#include <hip/hip_runtime.h>
#include <hip/hip_bf16.h>

typedef short  short8  __attribute__((ext_vector_type(8)));
typedef float  float4v __attribute__((ext_vector_type(4)));

#define SEQ    4096
#define DHEAD  64
#define NBLK   64
#define LSTR   72        // LDS row stride in bf16 elems for P buffer
#define NCHUNK 8         // split factor for full rows (qb 0, 63)
#define CHK    8         // key blocks per split chunk
#define WGPB   78        // units per (b,h): 62 regular + 2*8 split
#define ENTRY_FLOATS 4160   // per split-partial: 64 l + 64*64 o
#define KS_ELEMS (2L * 16 * 4096 * 64)   // bf16 K copy elems (= 16 MB)
// ws layout: [0,16MB) Ks bf16 | [16MB,32MB) VT bf16 | [32MB, ...) partials fp32

__device__ __forceinline__ short f2bf(float f) {
    unsigned u = __float_as_uint(f);
    u += 0x7fffu + ((u >> 16) & 1u);   // RNE to bf16
    return (short)(u >> 16);
}

// ---------------- prep: fp32 -> bf16, V transposed per 64x64 block ----------------
__global__ __launch_bounds__(256)
void bigbird_prep(const float* __restrict__ K,
                  const float* __restrict__ V,
                  short* __restrict__ wsS) {
    __shared__ float tile[64 * 65];
    const int bh = blockIdx.x >> 6;
    const int kb = blockIdx.x & 63;
    const int t  = threadIdx.x;
    short* Ks = wsS;
    short* VT = wsS + KS_ELEMS;

    const int row = t >> 2, seg = t & 3;
    const long gsrc = ((long)bh * SEQ + kb * 64 + row) * DHEAD + seg * 16;
    const long blk  = ((long)(bh * 64 + kb) * 64);

    // K: straight convert, coalesced
    {
        const float* kp = K + gsrc;
        short8 s0, s1;
#pragma unroll
        for (int i = 0; i < 4; ++i) {
            float4v x = ((const float4v*)kp)[i];
#pragma unroll
            for (int jj = 0; jj < 4; ++jj) {
                short v = f2bf(x[jj]);
                if (i < 2) s0[i * 4 + jj] = v; else s1[(i - 2) * 4 + jj] = v;
            }
        }
        *(short8*)(Ks + (blk + row) * 64 + seg * 16)     = s0;
        *(short8*)(Ks + (blk + row) * 64 + seg * 16 + 8) = s1;
    }
    // V: through LDS transpose
    {
        const float* vp = V + gsrc;
#pragma unroll
        for (int i = 0; i < 4; ++i) {
            float4v x = ((const float4v*)vp)[i];
#pragma unroll
            for (int jj = 0; jj < 4; ++jj)
                tile[row * 65 + seg * 16 + i * 4 + jj] = x[jj];
        }
    }
    __syncthreads();
    {
        const int d = t >> 2, kk = t & 3;
        short8 s0, s1;
#pragma unroll
        for (int i = 0; i < 8; ++i) {
            s0[i] = f2bf(tile[(kk * 16 + i) * 65 + d]);
            s1[i] = f2bf(tile[(kk * 16 + 8 + i) * 65 + d]);
        }
        *(short8*)(VT + (blk + d) * 64 + kk * 16)     = s0;
        *(short8*)(VT + (blk + d) * 64 + kk * 16 + 8) = s1;
    }
}

// ---------------- main: barrier-free, register-prefetched B-frags from bf16 ws ----
__global__ __launch_bounds__(256, 3)
void bigbird_main(const float* __restrict__ Q,
                  const int* __restrict__ rand_attn,
                  float* __restrict__ out,
                  const short* __restrict__ wsS,
                  float* __restrict__ part) {
    __shared__ short pb_s[4 * 16 * LSTR];   // per-wave P (wave-private slice)
    __shared__ int   kl_s[4][8];            // per-wave key-block list copy

    const int tid  = threadIdx.x;
    const int wave = tid >> 6;
    const int lane = tid & 63;
    const int l15  = lane & 15;
    const int quad = lane >> 4;

    // XCD-aware swizzle: all 78 units of a bh land on one XCD (4 bh per XCD);
    // each XCD's 4 MiB L2 then holds exactly its 4 bh x 1 MiB of ws.
    const int i    = blockIdx.x;
    const int xcd  = i & 7;
    const int slot = i >> 3;                // 0..311
    const int bh   = xcd + 8 * (slot / WGPB);
    const int j    = slot % WGPB;
    const bool split = (j >= 62);
    int qb, chunk = 0, nk;
    if (!split) { qb = j + 1; nk = (qb == 1 || qb == 62) ? 7 : 8; }
    else        { int s2 = j - 62; qb = (s2 >> 3) ? 63 : 0; chunk = s2 & 7; nk = CHK; }

    const long base = (long)bh * SEQ * DHEAD;
    const short* Ks = wsS + (long)bh * (NBLK * 64 * 64);
    const short* VT = wsS + KS_ELEMS + (long)bh * (NBLK * 64 * 64);

    // per-wave key-block list (same-wave write/read: lgkmcnt wait only, no barrier)
    if (!split && lane < 8) {
        const int rbase = (bh * 62 + (qb - 1)) * 3;
        int v = 0;
        if (qb == 1) {
            v = (lane == 0) ? 0 : (lane == 1) ? 1 : (lane == 2) ? 2 : (lane == 3) ? 63
                : (lane < 7 ? rand_attn[rbase + lane - 4] : 0);
        } else if (qb == 62) {
            v = (lane == 0) ? 0 : (lane == 1) ? 61 : (lane == 2) ? 62 : (lane == 3) ? 63
                : (lane < 7 ? rand_attn[rbase + lane - 4] : 0);
        } else {
            v = (lane == 0) ? 0 : (lane == 1) ? (qb - 1) : (lane == 2) ? qb
                : (lane == 3) ? (qb + 1) : (lane == 4) ? 63
                : rand_attn[rbase + lane - 5];
        }
        kl_s[wave][lane] = v;
    }

    // Q fragments from fp32, pre-scaled by 1/8 (exact); wave covers rows wave*16..+15
    short8 aq0, aq1;
    {
        const float* qp = Q + base + (long)(qb * 64 + wave * 16 + l15) * DHEAD + quad * 8;
        float4v x0 = *(const float4v*)(qp);
        float4v x1 = *(const float4v*)(qp + 4);
        float4v x2 = *(const float4v*)(qp + 32);
        float4v x3 = *(const float4v*)(qp + 36);
#pragma unroll
        for (int ii = 0; ii < 4; ++ii) {
            aq0[ii]     = f2bf(0.125f * x0[ii]);
            aq0[4 + ii] = f2bf(0.125f * x1[ii]);
            aq1[ii]     = f2bf(0.125f * x2[ii]);
            aq1[4 + ii] = f2bf(0.125f * x3[ii]);
        }
    }

    float4v o[4];
    float l_r[4];
#pragma unroll
    for (int nt = 0; nt < 4; ++nt) o[nt] = (float4v)0.0f;
#pragma unroll
    for (int r = 0; r < 4; ++r) l_r[r] = 0.0f;

    short* pw = pb_s + wave * (16 * LSTR);

    // fragment loaders: lane reads 16B at row (nt*16+l15), col quad*8 (+32)
    const int fofs = (int)l15 * 64 + quad * 8;
    auto loadK = [&](int kb, short8* k) {
        const short* p = Ks + (long)kb * 4096 + fofs;
#pragma unroll
        for (int nt = 0; nt < 4; ++nt) {
            k[nt * 2]     = *(const short8*)(p + nt * 1024);
            k[nt * 2 + 1] = *(const short8*)(p + nt * 1024 + 32);
        }
    };
    auto loadV = [&](int kb, short8* v) {
        const short* p = VT + (long)kb * 4096 + fofs;
#pragma unroll
        for (int nt = 0; nt < 4; ++nt) {
            v[nt * 2]     = *(const short8*)(p + nt * 1024);
            v[nt * 2 + 1] = *(const short8*)(p + nt * 1024 + 32);
        }
    };

    short8 kc[8], kn[8], vv[8];
    int kb_cur = split ? (chunk * CHK) : kl_s[wave][0];
    loadK(kb_cur, kc);

    for (int it = 0; it < nk; ++it) {
        // issue this iteration's V loads + next iteration's K loads up front (MLP)
        loadV(kb_cur, vv);
        int kb_nxt = kb_cur;
        const bool more = (it + 1 < nk);
        if (more) {
            kb_nxt = split ? (chunk * CHK + it + 1) : kl_s[wave][it + 1];
            loadK(kb_nxt, kn);
        }

        // ---- S = Q*K^T ----
        float4v s[4];
#pragma unroll
        for (int nt = 0; nt < 4; ++nt) {
            float4v acc = (float4v)0.0f;
            acc = __builtin_amdgcn_mfma_f32_16x16x32_bf16(aq0, kc[nt * 2], acc, 0, 0, 0);
            acc = __builtin_amdgcn_mfma_f32_16x16x32_bf16(aq1, kc[nt * 2 + 1], acc, 0, 0, 0);
            s[nt] = acc;
        }

        // ---- fixed-max softmax: P = exp(S); per-lane partial l ----
#pragma unroll
        for (int r = 0; r < 4; ++r) {
            float rs = 0.0f;
#pragma unroll
            for (int nt = 0; nt < 4; ++nt) {
                const float e = __expf(s[nt][r]);
                s[nt][r] = e;
                rs += e;
            }
            l_r[r] += rs;
#pragma unroll
            for (int nt = 0; nt < 4; ++nt)
                pw[(quad * 4 + r) * LSTR + nt * 16 + l15] = f2bf(s[nt][r]);
        }

        // ---- O += P*V ----
#pragma unroll
        for (int f = 0; f < 2; ++f) {
            short8 ap = *(const short8*)(pw + l15 * LSTR + f * 32 + quad * 8);
#pragma unroll
            for (int nt = 0; nt < 4; ++nt)
                o[nt] = __builtin_amdgcn_mfma_f32_16x16x32_bf16(ap, vv[nt * 2 + f], o[nt], 0, 0, 0);
        }

        if (more) {
#pragma unroll
            for (int q2 = 0; q2 < 8; ++q2) kc[q2] = kn[q2];
        }
        kb_cur = kb_nxt;
    }

    // reduce l across the quad's 16 lanes (once)
#pragma unroll
    for (int r = 0; r < 4; ++r) {
        float rs = l_r[r];
        rs += __shfl_xor(rs, 1, 64);
        rs += __shfl_xor(rs, 2, 64);
        rs += __shfl_xor(rs, 4, 64);
        rs += __shfl_xor(rs, 8, 64);
        l_r[r] = rs;
    }

    if (!split) {
        float* op = out + base + (long)(qb * 64 + wave * 16) * DHEAD;
#pragma unroll
        for (int r = 0; r < 4; ++r) {
            const float inv = 1.0f / l_r[r];
#pragma unroll
            for (int nt = 0; nt < 4; ++nt)
                op[(long)(quad * 4 + r) * DHEAD + nt * 16 + l15] = o[nt][r] * inv;
        }
    } else {
        float* wsp = part + (long)((bh * 2 + (qb == 63)) * NCHUNK + chunk) * ENTRY_FLOATS;
#pragma unroll
        for (int r = 0; r < 4; ++r) {
            const int row = wave * 16 + quad * 4 + r;
            if (l15 == 0) wsp[row] = l_r[r];
#pragma unroll
            for (int nt = 0; nt < 4; ++nt)
                wsp[64 + row * 64 + nt * 16 + l15] = o[nt][r];
        }
    }
}

// ---------------- combine for split rows (plain sums; fixed-max softmax) ----------------
__global__ __launch_bounds__(256)
void bigbird_combine(const float* __restrict__ part, float* __restrict__ out) {
    const int gid = blockIdx.x * 256 + threadIdx.x;   // 262144 total
    const int dim = gid & 63;
    const int row = (gid >> 6) & 63;
    const int sel = (gid >> 12) & 1;
    const int bh  = gid >> 13;

    float num = 0.0f, den = 0.0f;
#pragma unroll
    for (int c = 0; c < NCHUNK; ++c) {
        const float* e = part + (long)((bh * 2 + sel) * NCHUNK + c) * ENTRY_FLOATS;
        den += e[row];
        num += e[64 + row * 64 + dim];
    }
    const int qb = sel ? 63 : 0;
    out[((long)bh * SEQ + qb * 64 + row) * DHEAD + dim] = num / den;
}

extern "C" void kernel_launch(void* const* d_in, const int* in_sizes, int n_in,
                              void* d_out, int out_size, void* d_ws, size_t ws_size,
                              hipStream_t stream) {
    const float* Q       = (const float*)d_in[0];
    const float* K       = (const float*)d_in[1];
    const float* V       = (const float*)d_in[2];
    const int* rand_attn = (const int*)d_in[3];
    float* out           = (float*)d_out;
    short* wsS           = (short*)d_ws;
    float* part          = (float*)((char*)d_ws + 2L * KS_ELEMS * sizeof(short));

    const int B = 2, H = 16;
    bigbird_prep<<<dim3(B * H * NBLK), dim3(256), 0, stream>>>(K, V, wsS);
    bigbird_main<<<dim3(B * H * WGPB), dim3(256), 0, stream>>>(Q, rand_attn, out, wsS, part);
    bigbird_combine<<<dim3((B * H * 2 * 64 * 64) / 256), dim3(256), 0, stream>>>(part, out);
}

// Round 8
// 269.868 us; speedup vs baseline: 1.5113x; 1.3141x over previous
//
#include <hip/hip_runtime.h>
#include <hip/hip_bf16.h>

typedef short  short8  __attribute__((ext_vector_type(8)));
typedef float  float4v __attribute__((ext_vector_type(4)));

#define SEQ    4096
#define DHEAD  64
#define NBLK   64
#define LSTR   72        // LDS row stride in bf16 elems (144B; 16B-aligned, 2-way=free)
#define NCHUNK 8         // split factor for full rows (qb 0, 63)
#define CHK    8         // key blocks per split chunk
#define WGPB   78        // units per (b,h): 62 regular + 2*8 split
#define ENTRY_FLOATS 4160   // per split-partial: 64 l + 64*64 o
#define KS_ELEMS (2L * 16 * 4096 * 64)   // bf16 K copy elems (= 16 MB)
// ws layout: [0,16MB) Ks bf16 | [16MB,32MB) VT bf16 | [32MB, ...) partials fp32

__device__ __forceinline__ short f2bf(float f) {
    unsigned u = __float_as_uint(f);
    u += 0x7fffu + ((u >> 16) & 1u);   // RNE to bf16
    return (short)(u >> 16);
}

// ---------------- prep: fp32 -> bf16, V transposed per 64x64 block ----------------
__global__ __launch_bounds__(256)
void bigbird_prep(const float* __restrict__ K,
                  const float* __restrict__ V,
                  short* __restrict__ wsS) {
    __shared__ float tile[64 * 65];
    const int bh = blockIdx.x >> 6;
    const int kb = blockIdx.x & 63;
    const int t  = threadIdx.x;
    short* Ks = wsS;
    short* VT = wsS + KS_ELEMS;

    const int row = t >> 2, seg = t & 3;
    const long gsrc = ((long)bh * SEQ + kb * 64 + row) * DHEAD + seg * 16;
    const long blk  = ((long)(bh * 64 + kb) * 64);

    // K: straight convert, coalesced
    {
        const float* kp = K + gsrc;
        short8 s0, s1;
#pragma unroll
        for (int i = 0; i < 4; ++i) {
            float4v x = ((const float4v*)kp)[i];
#pragma unroll
            for (int jj = 0; jj < 4; ++jj) {
                short v = f2bf(x[jj]);
                if (i < 2) s0[i * 4 + jj] = v; else s1[(i - 2) * 4 + jj] = v;
            }
        }
        *(short8*)(Ks + (blk + row) * 64 + seg * 16)     = s0;
        *(short8*)(Ks + (blk + row) * 64 + seg * 16 + 8) = s1;
    }
    // V: through LDS transpose
    {
        const float* vp = V + gsrc;
#pragma unroll
        for (int i = 0; i < 4; ++i) {
            float4v x = ((const float4v*)vp)[i];
#pragma unroll
            for (int jj = 0; jj < 4; ++jj)
                tile[row * 65 + seg * 16 + i * 4 + jj] = x[jj];
        }
    }
    __syncthreads();
    {
        const int d = t >> 2, kk = t & 3;
        short8 s0, s1;
#pragma unroll
        for (int i = 0; i < 8; ++i) {
            s0[i] = f2bf(tile[(kk * 16 + i) * 65 + d]);
            s1[i] = f2bf(tile[(kk * 16 + 8 + i) * 65 + d]);
        }
        *(short8*)(VT + (blk + d) * 64 + kk * 16)     = s0;
        *(short8*)(VT + (blk + d) * 64 + kk * 16 + 8) = s1;
    }
}

// ---------------- main: round-4 staged-LDS structure + XCD-local L2 swizzle ----------
__global__ __launch_bounds__(256, 3)
void bigbird_main(const float* __restrict__ Q,
                  const int* __restrict__ rand_attn,
                  float* __restrict__ out,
                  const short* __restrict__ wsS,
                  float* __restrict__ part) {
    __shared__ short kb_s[2][64 * LSTR];   // K block (row-major), double-buffered
    __shared__ short vt_s[2][64 * LSTR];   // V^T block, double-buffered
    __shared__ short pb_s[4 * 16 * LSTR];  // per-wave P
    __shared__ int   kl[8];

    // XCD swizzle: all 78 units of a bh land on one XCD (4 bh per XCD);
    // each XCD's 4 MiB L2 then holds exactly its 4 bh x 1 MiB of bf16 K/V.
    const int gi   = blockIdx.x;
    const int xcd  = gi & 7;
    const int slot = gi >> 3;               // 0..311
    const int bh   = xcd + 8 * (slot / WGPB);
    const int j    = slot % WGPB;
    const bool split = (j >= 62);
    int qb, chunk = 0, nk;
    if (!split) { qb = j + 1; nk = (qb == 1 || qb == 62) ? 7 : 8; }
    else        { int s2 = j - 62; qb = (s2 >> 3) ? 63 : 0; chunk = s2 & 7; nk = CHK; }

    const int tid  = threadIdx.x;
    const int wave = tid >> 6;
    const int lane = tid & 63;
    const int l15  = lane & 15;
    const int quad = lane >> 4;

    const long base = (long)bh * SEQ * DHEAD;
    const short* Ks = wsS + (long)bh * (NBLK * 64 * 64);
    const short* VT = wsS + KS_ELEMS + (long)bh * (NBLK * 64 * 64);

    if (!split && tid < 8) {
        const int rbase = (bh * 62 + (qb - 1)) * 3;
        int v = 0;
        if (qb == 1) {
            v = (tid == 0) ? 0 : (tid == 1) ? 1 : (tid == 2) ? 2 : (tid == 3) ? 63
                : (tid < 7 ? rand_attn[rbase + tid - 4] : 0);
        } else if (qb == 62) {
            v = (tid == 0) ? 0 : (tid == 1) ? 61 : (tid == 2) ? 62 : (tid == 3) ? 63
                : (tid < 7 ? rand_attn[rbase + tid - 4] : 0);
        } else {
            v = (tid == 0) ? 0 : (tid == 1) ? (qb - 1) : (tid == 2) ? qb
                : (tid == 3) ? (qb + 1) : (tid == 4) ? 63
                : rand_attn[rbase + tid - 5];
        }
        kl[tid] = v;
    }

    // Q fragments from fp32, pre-scaled by 1/8 (exact); wave covers rows wave*16..+15
    short8 aq0, aq1;
    {
        const float* qp = Q + base + (long)(qb * 64 + wave * 16 + l15) * DHEAD + quad * 8;
        float4v x0 = *(const float4v*)(qp);
        float4v x1 = *(const float4v*)(qp + 4);
        float4v x2 = *(const float4v*)(qp + 32);
        float4v x3 = *(const float4v*)(qp + 36);
#pragma unroll
        for (int i = 0; i < 4; ++i) {
            aq0[i]     = f2bf(0.125f * x0[i]);
            aq0[4 + i] = f2bf(0.125f * x1[i]);
            aq1[i]     = f2bf(0.125f * x2[i]);
            aq1[4 + i] = f2bf(0.125f * x3[i]);
        }
    }

    const int vrow   = tid & 63;   // row (K) / d (VT) this thread stages
    const int vchunk = tid >> 6;   // 16-elem column group

    auto stage = [&](int kb, int buf) {
        const long blk = (long)(bh * 64 + kb) * 64 - (long)bh * (NBLK * 64 * 64);
        const short* kg = Ks + (long)(kb) * 4096 + vrow * 64 + vchunk * 16;
        const short* vg = VT + (long)(kb) * 4096 + vrow * 64 + vchunk * 16;
        (void)blk;
        short8 k0 = ((const short8*)kg)[0];
        short8 k1 = ((const short8*)kg)[1];
        short8 v0 = ((const short8*)vg)[0];
        short8 v1 = ((const short8*)vg)[1];
        *(short8*)&kb_s[buf][vrow * LSTR + vchunk * 16]     = k0;
        *(short8*)&kb_s[buf][vrow * LSTR + vchunk * 16 + 8] = k1;
        *(short8*)&vt_s[buf][vrow * LSTR + vchunk * 16]     = v0;
        *(short8*)&vt_s[buf][vrow * LSTR + vchunk * 16 + 8] = v1;
    };

    float4v o[4];
    float l_r[4];
#pragma unroll
    for (int nt = 0; nt < 4; ++nt) o[nt] = (float4v)0.0f;
#pragma unroll
    for (int r = 0; r < 4; ++r) l_r[r] = 0.0f;

    __syncthreads();                               // kl visible
    stage(split ? chunk * CHK : kl[0], 0);         // prologue
    __syncthreads();

    for (int it = 0; it < nk; ++it) {
        const int cur = it & 1;
        if (it + 1 < nk)                           // prefetch next block (overlaps compute)
            stage(split ? (chunk * CHK + it + 1) : kl[it + 1], cur ^ 1);

        // ---- S = Q*K^T from kb_s[cur] ----
        float4v s[4];
#pragma unroll
        for (int nt = 0; nt < 4; ++nt) {
            short8 b0 = *(const short8*)&kb_s[cur][(nt * 16 + l15) * LSTR + quad * 8];
            short8 b1 = *(const short8*)&kb_s[cur][(nt * 16 + l15) * LSTR + 32 + quad * 8];
            float4v acc = (float4v)0.0f;
            acc = __builtin_amdgcn_mfma_f32_16x16x32_bf16(aq0, b0, acc, 0, 0, 0);
            acc = __builtin_amdgcn_mfma_f32_16x16x32_bf16(aq1, b1, acc, 0, 0, 0);
            s[nt] = acc;
        }

        // ---- fixed-max softmax: P = exp(S); per-lane partial l ----
#pragma unroll
        for (int r = 0; r < 4; ++r) {
            float rs = 0.0f;
#pragma unroll
            for (int nt = 0; nt < 4; ++nt) {
                const float e = __expf(s[nt][r]);
                s[nt][r] = e;
                rs += e;
            }
            l_r[r] += rs;
#pragma unroll
            for (int nt = 0; nt < 4; ++nt)
                pb_s[wave * (16 * LSTR) + (quad * 4 + r) * LSTR + nt * 16 + l15] =
                    f2bf(s[nt][r]);
        }

        // ---- O += P*V ----
#pragma unroll
        for (int f = 0; f < 2; ++f) {
            short8 ap = *(const short8*)(pb_s + wave * (16 * LSTR) + l15 * LSTR +
                                         f * 32 + quad * 8);
#pragma unroll
            for (int nt = 0; nt < 4; ++nt) {
                short8 bv = *(const short8*)&vt_s[cur][(nt * 16 + l15) * LSTR +
                                                       f * 32 + quad * 8];
                o[nt] = __builtin_amdgcn_mfma_f32_16x16x32_bf16(ap, bv, o[nt], 0, 0, 0);
            }
        }
        __syncthreads();   // one barrier per iteration (buffer reuse distance 2)
    }

    // reduce l across the quad's 16 lanes (once)
#pragma unroll
    for (int r = 0; r < 4; ++r) {
        float rs = l_r[r];
        rs += __shfl_xor(rs, 1, 64);
        rs += __shfl_xor(rs, 2, 64);
        rs += __shfl_xor(rs, 4, 64);
        rs += __shfl_xor(rs, 8, 64);
        l_r[r] = rs;
    }

    if (!split) {
        float* op = out + base + (long)(qb * 64 + wave * 16) * DHEAD;
#pragma unroll
        for (int r = 0; r < 4; ++r) {
            const float inv = 1.0f / l_r[r];
#pragma unroll
            for (int nt = 0; nt < 4; ++nt)
                op[(long)(quad * 4 + r) * DHEAD + nt * 16 + l15] = o[nt][r] * inv;
        }
    } else {
        float* wsp = part + (long)((bh * 2 + (qb == 63)) * NCHUNK + chunk) * ENTRY_FLOATS;
#pragma unroll
        for (int r = 0; r < 4; ++r) {
            const int row = wave * 16 + quad * 4 + r;
            if (l15 == 0) wsp[row] = l_r[r];
#pragma unroll
            for (int nt = 0; nt < 4; ++nt)
                wsp[64 + row * 64 + nt * 16 + l15] = o[nt][r];
        }
    }
}

// ---------------- combine for split rows (plain sums; fixed-max softmax) ----------------
__global__ __launch_bounds__(256)
void bigbird_combine(const float* __restrict__ part, float* __restrict__ out) {
    const int gid = blockIdx.x * 256 + threadIdx.x;   // 262144 total
    const int dim = gid & 63;
    const int row = (gid >> 6) & 63;
    const int sel = (gid >> 12) & 1;
    const int bh  = gid >> 13;

    float num = 0.0f, den = 0.0f;
#pragma unroll
    for (int c = 0; c < NCHUNK; ++c) {
        const float* e = part + (long)((bh * 2 + sel) * NCHUNK + c) * ENTRY_FLOATS;
        den += e[row];
        num += e[64 + row * 64 + dim];
    }
    const int qb = sel ? 63 : 0;
    out[((long)bh * SEQ + qb * 64 + row) * DHEAD + dim] = num / den;
}

extern "C" void kernel_launch(void* const* d_in, const int* in_sizes, int n_in,
                              void* d_out, int out_size, void* d_ws, size_t ws_size,
                              hipStream_t stream) {
    const float* Q       = (const float*)d_in[0];
    const float* K       = (const float*)d_in[1];
    const float* V       = (const float*)d_in[2];
    const int* rand_attn = (const int*)d_in[3];
    float* out           = (float*)d_out;
    short* wsS           = (short*)d_ws;
    float* part          = (float*)((char*)d_ws + 2L * KS_ELEMS * sizeof(short));

    const int B = 2, H = 16;
    bigbird_prep<<<dim3(B * H * NBLK), dim3(256), 0, stream>>>(K, V, wsS);
    bigbird_main<<<dim3(B * H * WGPB), dim3(256), 0, stream>>>(Q, rand_attn, out, wsS, part);
    bigbird_combine<<<dim3((B * H * 2 * 64 * 64) / 256), dim3(256), 0, stream>>>(part, out);
}